// Round 1
// 323.553 us; speedup vs baseline: 1.0409x; 1.0409x over previous
//
#include <hip/hip_runtime.h>
#include <hip/hip_bf16.h>

// PPNet head for MI355X, round 4.
// prep -> fused (conv implicit-GEMM bf16 MFMA -> LDS f bounce -> pp MFMA cc
//                + log acts + fused max partials, all in one block)
//      -> pool -> logits.
// R3 split conv/pp via a 75 MB f_bf+ps HBM round-trip; fused here: conv's
// 256-pixel tile is exactly pp's working set, and each wave pp's the same
// pixels it conv'd, so f bounces through LDS (swizzled) and ps stays in
// registers after the quad-fold shuffle.

#define N_P   190
#define N_CLS 19
#define N_B   16
#define EPS_F 1e-4f

typedef unsigned short ushort_t;
typedef unsigned int   uint_t;
typedef __attribute__((ext_vector_type(8))) short bf16x8;
typedef __attribute__((ext_vector_type(4))) float f32x4;

__device__ __forceinline__ ushort_t bf16_rne(float v) {
    uint_t u = __float_as_uint(v);
    u += 0x7fffu + ((u >> 16) & 1u);
    return (ushort_t)(u >> 16);
}
__device__ __forceinline__ uint_t pack2(float a, float b) {
    return (uint_t)bf16_rne(a) | ((uint_t)bf16_rne(b) << 16);
}

// ---------------- prep ------------------------------------------------------
// wf[kr][co][kw'] bf16, kr in [0,24), kw' in [0,8):
//   kw'=0 or kr>=21 -> 0; else w[co][ci*49+kh*7+(kw'-1)], (ci,kh) = kr /% 7.
// Zero weight columns absorb all K-padding so conv's A-gather needs no masks.
// Also proto_bf (padded to 192) and fsum.
__global__ void prep_kernel(const float* __restrict__ feat_w,
                            const float* __restrict__ proto,
                            ushort_t* __restrict__ wf,
                            ushort_t* __restrict__ proto_bf,
                            float* __restrict__ fsum) {
    int t = blockIdx.x * 256 + threadIdx.x;   // grid 48*256 = 12288
    if (t < 12288) {
        int kr = t >> 9, co = (t >> 3) & 63, kwp = t & 7;
        float v = 0.f;
        if (kr < 21 && kwp >= 1) {
            int ci = kr / 7, kh = kr - ci * 7;
            v = feat_w[co * 147 + ci * 49 + kh * 7 + (kwp - 1)];
        }
        wf[t] = bf16_rne(v);
        int p = t >> 6, c = t & 63;
        proto_bf[t] = bf16_rne((p < N_P) ? proto[p * 64 + c] : 0.f);
    }
    if (t < 192) {
        float s = 0.f;
        if (t < N_P)
            for (int c = 0; c < 64; ++c) {
                float v = proto[t * 64 + c];
                s = fmaf(v, v, s);
            }
        fsum[t] = s;
    }
}

// ---------------- fused: conv + sigmoid + prototype distances --------------
// Block = 4 waves = 2 output rows (oh pair); conv wave = 1 row-half:
// 64 pix x 64 co.  LDS: x as bf16, 33 rows (3ci x 11ih) x 520 (4-elem left
// pad -> all b64 staging writes and patch gathers 8B-aligned).
// After the conv MFMA loop, f (bias+sigmoid, bf16) is bounced through the
// SAME LDS buffer as [pix][64ch], 128B rows, byte-offset XOR-swizzled with
// (pix&7)<<4 so the 16 scattered uint2 writes and the b128 fragment reads
// stay (mostly) conflict-free.  Each wave then pp's its own 64 pixels:
// 12 proto tiles x (4 s x 2 MFMA), log acts direct to output, per-tile max
// partials to 256 slots/(b,p).  ps never touches global: the cross-quad
// shfl fold leaves the full 64-ch sum in EVERY lane.
#define XW 520
__global__ __launch_bounds__(256) void fused_kernel(
        const float* __restrict__ x,
        const ushort_t* __restrict__ wf,
        const float* __restrict__ bias,
        const ushort_t* __restrict__ proto_bf,
        const float* __restrict__ fsum,
        float* __restrict__ acts,
        float* __restrict__ partial) {
    __shared__ alignas(16) ushort_t xs[33 * XW];   // 34,320 B; f overlay needs 32,768 B
    const int b  = blockIdx.x >> 6;
    const int op = blockIdx.x & 63;
    const int tid = threadIdx.x;

    if (tid < 33) *(uint2*)(xs + tid * XW) = make_uint2(0u, 0u);  // left pad
    const int base_ih = op * 8 - 3;
    for (int i = tid; i < 33 * 128; i += 256) {
        int row = i >> 7;
        int c4  = (i & 127) << 2;
        int ci  = (row * 94) >> 10;      // row/11 for row<33
        int ihr = row - ci * 11;
        int ih  = base_ih + ihr;
        float4 v = make_float4(0.f, 0.f, 0.f, 0.f);
        if (ih >= 0 && ih < 512)
            v = *(const float4*)(x + (((b * 3 + ci) * 512 + ih) << 9) + c4);
        uint2 pk = make_uint2(pack2(v.x, v.y), pack2(v.z, v.w));
        *(uint2*)(xs + row * XW + c4 + 4) = pk;   // byte = row*1040 + 2*c4+8, 8B-aligned
    }
    __syncthreads();

    const int lane = tid & 63, wave = tid >> 6;
    const int n = lane & 15, quad = lane >> 4;
    const int oh_l = wave >> 1, owb = (wave & 1) << 6;

    f32x4 acc[4][4];
#pragma unroll
    for (int ms = 0; ms < 4; ++ms)
#pragma unroll
        for (int ns = 0; ns < 4; ++ns) acc[ms][ns] = (f32x4){0.f, 0.f, 0.f, 0.f};

#pragma unroll
    for (int c = 0; c < 6; ++c) {
        const int kr  = c * 4 + quad;               // k-row 0..23
        const int kra = (kr < 21) ? kr : 0;         // clamp; B weight rows >=21 are 0
        const int ci  = (kra * 37) >> 8;            // kra/7
        const int kh  = kra - ci * 7;
        const ushort_t* bb = xs + (ci * 11 + oh_l * 4 + kh) * XW;

        bf16x8 afr[4], bfr[4];
        const ushort_t* wbase = wf + (kr << 9) + (n << 3);
#pragma unroll
        for (int ms = 0; ms < 4; ++ms)
            afr[ms] = *(const bf16x8*)(wbase + (ms << 7));   // 16B aligned
#pragma unroll
        for (int ns = 0; ns < 4; ++ns) {
            const ushort_t* p8 = bb + ((owb + ns * 16 + n) << 2);  // 8B aligned
            union { uint2 u[2]; bf16x8 v; } t2;
            t2.u[0] = *(const uint2*)(p8);
            t2.u[1] = *(const uint2*)(p8 + 4);
            bfr[ns] = t2.v;
        }
#pragma unroll
        for (int ms = 0; ms < 4; ++ms)
#pragma unroll
            for (int ns = 0; ns < 4; ++ns)
                acc[ms][ns] = __builtin_amdgcn_mfma_f32_16x16x32_bf16(
                    afr[ms], bfr[ns], acc[ms][ns], 0, 0, 0);
    }

    __syncthreads();   // everyone done reading xs before the f overlay

    // Epilogue: lane holds co = ms*16+quad*4+r, pixel = owb+ns*16+n.
    // Write f bf16 to LDS (swizzled), accumulate ps in registers.
    char* fls = (char*)xs;
    float psl[4] = {0.f, 0.f, 0.f, 0.f};
#pragma unroll
    for (int ms = 0; ms < 4; ++ms) {
        float4 bv = *(const float4*)(bias + ms * 16 + quad * 4);
        const float* bvp = (const float*)&bv;
#pragma unroll
        for (int ns = 0; ns < 4; ++ns) {
            float fr[4];
#pragma unroll
            for (int r = 0; r < 4; ++r) {
                float z = acc[ms][ns][r] + bvp[r];
                float f = 1.f / (1.f + __expf(-z));
                fr[r] = f;
                psl[ns] = fmaf(f, f, psl[ns]);
            }
            int pix = wave * 64 + ns * 16 + n;                // block-local 0..255
            int off = (ms * 32 + quad * 8) ^ ((pix & 7) << 4);  // swizzled byte in 128B row
            *(uint2*)(fls + pix * 128 + off) = make_uint2(pack2(fr[0], fr[1]), pack2(fr[2], fr[3]));
        }
    }
    float psv[4];
#pragma unroll
    for (int ns = 0; ns < 4; ++ns) {   // fold quads -> full 64-co sum in EVERY lane
        float v = psl[ns];
        v += __shfl_xor(v, 16, 64);
        v += __shfl_xor(v, 32, 64);
        psv[ns] = v;
    }
    __syncthreads();   // belt-and-braces (each wave reads only its own writes)

    // ---- phase B: wave pp's its own 64 pixels over 192 protos ----
    bf16x8 bfr2[4][2];
#pragma unroll
    for (int s = 0; s < 4; ++s) {
        int pix = wave * 64 + s * 16 + n;
        int sw = (pix & 7) << 4;
        bfr2[s][0] = *(const bf16x8*)(fls + pix * 128 + ((quad * 16) ^ sw));
        bfr2[s][1] = *(const bf16x8*)(fls + pix * 128 + ((64 + quad * 16) ^ sw));
    }
    const int oh = op * 2 + oh_l;
    const int cb = oh * 128 + owb;      // within-plane offset base; + s*16+n

    for (int pt = 0; pt < 12; ++pt) {
        const int p0 = pt * 16;
        const ushort_t* ap = proto_bf + (p0 + n) * 64 + quad * 8;
        bf16x8 a0 = *(const bf16x8*)ap;
        bf16x8 a1 = *(const bf16x8*)(ap + 32);
        float4 fsv = *(const float4*)(fsum + p0 + quad * 4);
        const float* fsp = (const float*)&fsv;

        float mx[4] = {-1e30f, -1e30f, -1e30f, -1e30f};
#pragma unroll
        for (int s = 0; s < 4; ++s) {
            f32x4 acc2 = (f32x4){0.f, 0.f, 0.f, 0.f};
            acc2 = __builtin_amdgcn_mfma_f32_16x16x32_bf16(a0, bfr2[s][0], acc2, 0, 0, 0);
            acc2 = __builtin_amdgcn_mfma_f32_16x16x32_bf16(a1, bfr2[s][1], acc2, 0, 0, 0);
#pragma unroll
            for (int r = 0; r < 4; ++r) {
                float d = fmaf(-2.f, acc2[r], psv[s] + fsp[r]);
                float act = __logf(__fdividef(d + 1.f, d + EPS_F));
                mx[r] = fmaxf(mx[r], act);
                int p = p0 + quad * 4 + r;
                if (p < N_P)
                    acts[((long)(b * N_P + p) << 14) + cb + s * 16 + n] = act;
            }
        }
#pragma unroll
        for (int r = 0; r < 4; ++r) {   // max over the wave's 64 pixels
            float m = mx[r];
            m = fmaxf(m, __shfl_xor(m, 1, 64));
            m = fmaxf(m, __shfl_xor(m, 2, 64));
            m = fmaxf(m, __shfl_xor(m, 4, 64));
            m = fmaxf(m, __shfl_xor(m, 8, 64));
            if (n == 0)
                partial[((long)(b * 192 + p0 + quad * 4 + r) << 8) + op * 4 + wave] = m;
        }
    }
}

// ---------------- pool: 256-way max per (b,p) ------------------------------
__global__ void pool_kernel(const float* __restrict__ partial,
                            float* __restrict__ pooled) {
    const int idx = blockIdx.x;               // b*190 + p
    const int b = idx / 190, p = idx - b * 190;
    const float4* base = (const float4*)(partial + ((long)(b * 192 + p) << 8));
    const int t = threadIdx.x;                // 64
    float4 v0 = base[t];
    float m = fmaxf(fmaxf(v0.x, v0.y), fmaxf(v0.z, v0.w));
#pragma unroll
    for (int off = 32; off; off >>= 1) m = fmaxf(m, __shfl_xor(m, off, 64));
    if (t == 0) pooled[idx] = m;
}

// ---------------- logits ---------------------------------------------------
__global__ void logits_kernel(const float* __restrict__ pooled,
                              const float* __restrict__ last_w,
                              float* __restrict__ logits) {
    int t = blockIdx.x * blockDim.x + threadIdx.x;
    if (t >= N_B * N_CLS) return;
    int b = t / N_CLS, cls = t - b * N_CLS;
    float s = 0.f;
    for (int p = 0; p < N_P; ++p)
        s = fmaf(pooled[b * N_P + p], last_w[cls * N_P + p], s);
    logits[t] = s;
}

extern "C" void kernel_launch(void* const* d_in, const int* in_sizes, int n_in,
                              void* d_out, int out_size, void* d_ws, size_t ws_size,
                              hipStream_t stream) {
    const float* x      = (const float*)d_in[0];  // (16,3,512,512)
    const float* feat_w = (const float*)d_in[1];  // (64,3,7,7)
    const float* feat_b = (const float*)d_in[2];  // (64,)
    const float* proto  = (const float*)d_in[3];  // (190,64,1,1)
    const float* last_w = (const float*)d_in[4];  // (19,190)

    float* out_logits = (float*)d_out;                 // 304
    float* out_acts   = (float*)d_out + N_B * N_CLS;   // 16*190*128*128

    char* ws = (char*)d_ws;
    float*    partial  = (float*)(ws);                       //  3,145,728 B (16*192*256)
    ushort_t* wf       = (ushort_t*)(ws + 3145728);          //     24,576 B
    ushort_t* proto_bf = (ushort_t*)(ws + 3170304);          //     24,576 B
    float*    fsum     = (float*)(ws + 3194880);             //        768 B
    float*    pooled   = (float*)(ws + 3195648);             //     12,160 B

    prep_kernel<<<48, 256, 0, stream>>>(feat_w, proto, wf, proto_bf, fsum);
    fused_kernel<<<N_B * 64, 256, 0, stream>>>(x, wf, feat_b, proto_bf, fsum, out_acts, partial);
    pool_kernel<<<N_B * N_P, 64, 0, stream>>>(partial, pooled);
    logits_kernel<<<2, 256, 0, stream>>>(pooled, last_w, out_logits);
}